// Round 17
// baseline (3724.916 us; speedup 1.0000x reference)
//
#include <hip/hip_runtime.h>
#include <math.h>

// Problem constants
#define NL    1568          // left nodes (B*P)
#define NTOT  3136          // total nodes
#define DD    768           // feature dim
#define NH    12            // heads
#define DHD   64            // head dim
#define WPR   49            // mask words per row (1568/32)
#define MAXDEG 64           // neighbor-list capacity
#define NKSTEP 24           // 768 / 32
#define LISTCAP 16384       // borderline-pair list capacity (~760 expected)
#define GRID_MEGA 588       // <= 256 CU x 3 blocks/CU = 768 -> all co-resident
#define LOG2F_ 0.69314718055994530942f

typedef _Float16 h8 __attribute__((ext_vector_type(8)));
typedef float f32x4 __attribute__((ext_vector_type(4)));
#define MFMA16(a, b, c) __builtin_amdgcn_mfma_f32_16x16x32_f16(a, b, c, 0, 0, 0)

__device__ __forceinline__ float leaky(float x) { return x > 0.f ? x : 0.2f * x; }

__device__ __forceinline__ void gld16(const _Float16* g, _Float16* l) {
  __builtin_amdgcn_global_load_lds(
      (const __attribute__((address_space(1))) void*)g,
      (__attribute__((address_space(3))) void*)l, 16, 0, 0);
}

// software grid barrier (residency guaranteed: grid 588 <= 768 co-resident).
// release fence -> device-scope arrive -> agent-scope acquire poll -> fence.
__device__ __forceinline__ void gridbar(unsigned* bar, int idx) {
  __syncthreads();
  __threadfence();                        // release: flush this block's writes device-wide
  if (threadIdx.x == 0) {
    atomicAdd(&bar[idx], 1u);             // device-scope
    while (__hip_atomic_load(&bar[idx], __ATOMIC_ACQUIRE, __HIP_MEMORY_SCOPE_AGENT) < GRID_MEGA)
      __builtin_amdgcn_s_sleep(8);
  }
  __syncthreads();
  __threadfence();                        // acquire: invalidate stale cache lines before reads
}

// ---------------------------------------------------------------- inputs -> fp16 hi plane + row norms (fused)
__global__ __launch_bounds__(192) void conv_init(const float* __restrict__ lf, const float* __restrict__ rf,
                                                 _Float16* __restrict__ hi, float* __restrict__ norms) {
  int n = blockIdx.x;
  int t = threadIdx.x;
  const float* src = (n < NL) ? lf + (size_t)n * DD : rf + (size_t)(n - NL) * DD;
  float4 v = reinterpret_cast<const float4*>(src)[t];
  typedef _Float16 h4v __attribute__((ext_vector_type(4)));
  h4v hv = {(_Float16)v.x, (_Float16)v.y, (_Float16)v.z, (_Float16)v.w};
  reinterpret_cast<h4v*>(hi)[(size_t)n * (DD / 4) + t] = hv;
  float s = v.x * v.x + v.y * v.y + v.z * v.z + v.w * v.w;
  #pragma unroll
  for (int o = 32; o; o >>= 1) s += __shfl_xor(s, o);
  __shared__ float red[3];
  if ((t & 63) == 0) red[t >> 6] = s;
  __syncthreads();
  if (t == 0) norms[n] = sqrtf(red[0] + red[1] + red[2]);
}

// ---------------------------------------------------------------- W[i][k][n] -> Wt[i][n][k] fp16 (hi only)
__global__ __launch_bounds__(256) void transp_W(const float* __restrict__ W, _Float16* __restrict__ Wthi) {
  __shared__ float tile[32][33];
  int kt = blockIdx.x * 32, nt = blockIdx.y * 32, i = blockIdx.z;
  int tx = threadIdx.x & 31, ty = threadIdx.x >> 5;
  const float* Wp = W + ((size_t)i * DD + kt) * DD + nt;
  #pragma unroll
  for (int p = 0; p < 4; ++p) tile[ty + p * 8][tx] = Wp[(size_t)(ty + p * 8) * DD + tx];
  __syncthreads();
  _Float16* oh = Wthi + ((size_t)i * DD + nt) * DD + kt;
  #pragma unroll
  for (int p = 0; p < 4; ++p) {
    int nn = ty + p * 8;
    oh[(size_t)nn * DD + tx] = (_Float16)tile[tx][nn];
  }
}

// ---------------------------------------------------------------- mask via hi-only MFMA; borderline pairs -> list
__global__ __launch_bounds__(256) void mask_mfma(const _Float16* __restrict__ Hhi,
                                                 const float* __restrict__ norms, unsigned* __restrict__ mask,
                                                 unsigned* __restrict__ bcnt, int2* __restrict__ blist) {
  __shared__ _Float16 sm[2][2][2048];
  __shared__ unsigned mw[64][2];
  int t = threadIdx.x;
  int r0 = blockIdx.x * 64, l0 = blockIdx.y * 64;

  int rl = t >> 2;
  int kq_src = (t & 3) ^ ((t >> 3) & 3);
  int ra = r0 + rl; if (ra >= NL) ra = NL - 1;
  int la = l0 + rl; if (la >= NL) la = NL - 1;
  const _Float16* pA = Hhi + (size_t)(NL + ra) * DD + kq_src * 8;
  const _Float16* pB = Hhi + (size_t)la * DD + kq_src * 8;
  int ch = (t >> 6) * 512;

  int ln = t & 63, wv = t >> 6;
  int fr = ln & 15, kg = ln >> 4;
  int kq8 = (kg ^ ((fr >> 1) & 3)) * 8;
  int aRead = (wv * 16 + fr) * 32 + kq8;

  f32x4 zero = {0.f, 0.f, 0.f, 0.f};
  f32x4 acc[4];
  #pragma unroll
  for (int cg = 0; cg < 4; ++cg) acc[cg] = zero;
  if (t < 128) mw[t >> 1][t & 1] = 0u;

  gld16(pA, &sm[0][0][ch]);
  gld16(pB, &sm[0][1][ch]);
  __syncthreads();

  for (int step = 0; step < NKSTEP; ++step) {
    int buf = step & 1;
    if (step < NKSTEP - 1) {
      int kb = (step + 1) * 32;
      gld16(pA + kb, &sm[buf ^ 1][0][ch]);
      gld16(pB + kb, &sm[buf ^ 1][1][ch]);
    }
    h8 ah = *reinterpret_cast<const h8*>(&sm[buf][0][aRead]);
    #pragma unroll
    for (int cg = 0; cg < 4; ++cg) {
      int bRead = (cg * 16 + fr) * 32 + kq8;
      h8 bh = *reinterpret_cast<const h8*>(&sm[buf][1][bRead]);
      acc[cg] = MFMA16(ah, bh, acc[cg]);
    }
    __syncthreads();
  }

  int rloc = wv * 16 + kg * 4;
  float nrv[4];
  #pragma unroll
  for (int i = 0; i < 4; ++i) {
    int r = r0 + rloc + i;
    nrv[i] = norms[NL + (r < NL ? r : NL - 1)];
  }
  #pragma unroll
  for (int cg = 0; cg < 4; ++cg) {
    int lloc = cg * 16 + fr;
    int l = l0 + lloc;
    float nlv = norms[l < NL ? l : NL - 1];
    #pragma unroll
    for (int i = 0; i < 4; ++i) {
      int r = r0 + rloc + i;
      if (r >= NL || l >= NL) continue;
      float thr = 0.1f * nrv[i] * nlv;
      float dot = acc[cg][i];
      if (fabsf(dot - thr) <= 0.5f) {
        unsigned pos = atomicAdd(bcnt, 1u);
        if (pos < LISTCAP) blist[pos] = make_int2(r, l);
      }
      if (dot > thr) atomicOr(&mw[rloc + i][lloc >> 5], 1u << (lloc & 31));
    }
  }
  __syncthreads();
  if (t < 128) {
    int rr = t >> 1, w = t & 1;
    int rg = r0 + rr, wg = blockIdx.y * 2 + w;
    if (rg < NL && wg < WPR) mask[(size_t)rg * WPR + wg] = mw[rr][w];
  }
}

// ---------------------------------------------------------------- exact fp32 recheck of borderline pairs (wave/pair)
__global__ __launch_bounds__(256) void mask_fix(const float* __restrict__ lf, const float* __restrict__ rf,
                                                const float* __restrict__ norms,
                                                const unsigned* __restrict__ bcnt, const int2* __restrict__ blist,
                                                unsigned* __restrict__ mask) {
  unsigned cnt = *bcnt;
  if (cnt > LISTCAP) cnt = LISTCAP;
  int lane = threadIdx.x & 63;
  unsigned wid = blockIdx.x * 4 + (threadIdx.x >> 6);
  for (unsigned idx = wid; idx < cnt; idx += gridDim.x * 4) {
    int2 pr = blist[idx];
    int r = pr.x, l = pr.y;
    const float4* rp = reinterpret_cast<const float4*>(rf + (size_t)r * DD);
    const float4* lp = reinterpret_cast<const float4*>(lf + (size_t)l * DD);
    float s = 0.f;
    #pragma unroll
    for (int k = 0; k < 3; ++k) {
      float4 a = rp[lane + k * 64], b = lp[lane + k * 64];
      s = fmaf(a.x, b.x, s); s = fmaf(a.y, b.y, s);
      s = fmaf(a.z, b.z, s); s = fmaf(a.w, b.w, s);
    }
    #pragma unroll
    for (int o = 32; o; o >>= 1) s += __shfl_xor(s, o);
    if (lane == 0) {
      float thr = 0.1f * norms[NL + r] * norms[l];
      unsigned* wp = &mask[(size_t)r * WPR + (l >> 5)];
      unsigned bit = 1u << (l & 31);
      if (s > thr) atomicOr(wp, bit);
      else atomicAnd(wp, ~bit);
    }
  }
}

// ---------------------------------------------------------------- build neighbor lists from bitmask (once)
__global__ __launch_bounds__(64) void build_csr(const unsigned* __restrict__ mask,
                                                int* __restrict__ nbr, int* __restrict__ deg) {
  int r = blockIdx.x * 64 + threadIdx.x;
  if (r >= NL) return;
  const unsigned* mr = mask + (size_t)r * WPR;
  int* out = nbr + (size_t)r * MAXDEG;
  int cnt = 0;
  #pragma unroll 7
  for (int w = 0; w < WPR; ++w) {
    unsigned m = mr[w];
    while (m) {
      int bpos = __ffs(m) - 1;
      m &= m - 1;
      if (cnt < MAXDEG) out[cnt] = w * 32 + bpos;
      ++cnt;
    }
  }
  deg[r] = cnt < MAXDEG ? cnt : MAXDEG;
}

// ---------------------------------------------------------------- persistent mega-kernel: 8 layers, spin grid barrier
// grid 588 x 256 thr, 3 blocks/CU (all co-resident). gemm = R14 tile per block; bip = 3 cols/thread; pool on blocks 0..191.
__global__ __launch_bounds__(256, 3) void mega(_Float16* __restrict__ hhiA, _Float16* __restrict__ hhiB,
                                               const _Float16* __restrict__ Wthi,
                                               const float* __restrict__ a_src, const float* __restrict__ a_dst,
                                               const float* __restrict__ bvec,
                                               _Float16* __restrict__ zh, float* __restrict__ el, float* __restrict__ er,
                                               const int* __restrict__ nbr, const int* __restrict__ deg,
                                               float* __restrict__ out, float* __restrict__ hroot,
                                               unsigned* __restrict__ gbar) {
  __shared__ _Float16 sm[2][2][2048];    // gemm staging (16 KB)
  __shared__ int nb_s[MAXDEG];           // bip
  __shared__ float wbuf[MAXDEG * NH];
  __shared__ float den_s[NH], wself_s[NH];
  __shared__ float wb[196];              // pool
  __shared__ float red4[4];
  __shared__ float accP[4][64];

  int t = threadIdx.x;
  // gemm per-thread constants
  int rl = t >> 2;
  int kq_src = (t & 3) ^ ((t >> 3) & 3);
  int ln = t & 63, wv = t >> 6;
  int fr = ln & 15, kg = ln >> 4;
  int kq8 = (kg ^ ((fr >> 1) & 3)) * 8;
  int aRead = (wv * 16 + fr) * 32 + kq8;
  int ch = wv * 512;
  // bijective XCD swizzle: 588 = 4*74 + 4*73
  int xcd = blockIdx.x & 7, pos = blockIdx.x >> 3;
  int orig = (xcd < 4 ? xcd * 74 : 296 + (xcd - 4) * 73) + pos;
  int bx = orig / 12, by = orig % 12;
  int m0 = bx * 64, n0 = by * 64;

  for (int L = 0; L < 8; ++L) {
    int i = (L < 4) ? L : L - 4;
    int mode = (L < 4) ? 0 : 1;
    int do_elu = (i < 3) ? 1 : 0;
    _Float16* Ah = (L & 1) ? hhiB : hhiA;
    _Float16* Oh = (L & 1) ? hhiA : hhiB;
    const _Float16* Bw = Wthi + (size_t)i * DD * DD;
    const float* a_s = a_src + (size_t)i * NH * DHD;
    const float* a_d = a_dst + (size_t)i * NH * DHD;
    const float* bias = bvec + (size_t)i * DD;

    // ================= GEMM phase (one 64x64 tile per block) =================
    {
      const _Float16* pA = Ah + (size_t)(m0 + rl) * DD + kq_src * 8;
      const _Float16* pB = Bw + (size_t)(n0 + rl) * DD + kq_src * 8;
      f32x4 zero = {0.f, 0.f, 0.f, 0.f};
      f32x4 acc[4];
      #pragma unroll
      for (int cgi = 0; cgi < 4; ++cgi) acc[cgi] = zero;

      gld16(pA, &sm[0][0][ch]);
      gld16(pB, &sm[0][1][ch]);
      __syncthreads();
      for (int step = 0; step < NKSTEP; ++step) {
        int buf = step & 1;
        if (step < NKSTEP - 1) {
          int kb = (step + 1) * 32;
          gld16(pA + kb, &sm[buf ^ 1][0][ch]);
          gld16(pB + kb, &sm[buf ^ 1][1][ch]);
        }
        h8 ah = *reinterpret_cast<const h8*>(&sm[buf][0][aRead]);
        #pragma unroll
        for (int cgi = 0; cgi < 4; ++cgi) {
          int bRead = (cgi * 16 + fr) * 32 + kq8;
          h8 bh = *reinterpret_cast<const h8*>(&sm[buf][1][bRead]);
          acc[cgi] = MFMA16(ah, bh, acc[cgi]);
        }
        __syncthreads();
      }
      int orow = m0 + wv * 16 + kg * 4;
      #pragma unroll
      for (int ii = 0; ii < 4; ++ii) {
        int r = orow + ii;
        bool wh = (mode == 0) ? (r < NL) : (r % 196 != 0);
        #pragma unroll
        for (int cgi = 0; cgi < 4; ++cgi) {
          int c = n0 + cgi * 16 + fr;
          float z = acc[cgi][ii];
          zh[(size_t)r * DD + c] = (_Float16)z;
          if (wh) {
            float o = z + bias[c];
            if (do_elu) o = o > 0.f ? o : expm1f(o);
            Oh[(size_t)r * DD + c] = (_Float16)o;
          }
        }
      }
      float asv[4], adv[4];
      #pragma unroll
      for (int cgi = 0; cgi < 4; ++cgi) {
        asv[cgi] = a_s[by * DHD + cgi * 16 + fr];
        adv[cgi] = a_d[by * DHD + cgi * 16 + fr];
      }
      #pragma unroll
      for (int ii = 0; ii < 4; ++ii) {
        float s1 = 0.f, s2 = 0.f;
        #pragma unroll
        for (int cgi = 0; cgi < 4; ++cgi) {
          s1 = fmaf(acc[cgi][ii], asv[cgi], s1);
          s2 = fmaf(acc[cgi][ii], adv[cgi], s2);
        }
        #pragma unroll
        for (int o = 1; o < 16; o <<= 1) {
          s1 += __shfl_xor(s1, o);
          s2 += __shfl_xor(s2, o);
        }
        if (fr == 0) {
          el[(size_t)(orow + ii) * NH + by] = s1;
          er[(size_t)(orow + ii) * NH + by] = s2;
        }
      }
    }
    gridbar(gbar, 2 * L);

    // ================= Attention phase =================
    if (mode == 0) {
      for (int r = blockIdx.x; r < NL; r += GRID_MEGA) {
        int R = NL + r;
        int dg = deg[r];
        __syncthreads();                       // protect LDS reuse across r-iterations
        for (int e = t; e < dg; e += 256) nb_s[e] = nbr[(size_t)r * MAXDEG + e];
        __syncthreads();
        for (int e = t; e < dg * NH; e += 256) {
          int j = e / NH, h2 = e - j * NH;
          wbuf[e] = el[(size_t)nb_s[j] * NH + h2];
        }
        __syncthreads();
        if (t < NH) {
          float er_r = er[(size_t)R * NH + t];
          float s = leaky(el[(size_t)R * NH + t] + er_r);
          float mx = s;
          for (int j = 0; j < dg; ++j) mx = fmaxf(mx, leaky(wbuf[j * NH + t] + er_r));
          float den = 0.f;
          for (int j = 0; j < dg; ++j) {
            float w = expf(leaky(wbuf[j * NH + t] + er_r) - mx);
            wbuf[j * NH + t] = w;
            den += w;
          }
          float ws = expf(s - mx);
          den_s[t] = den + ws;
          wself_s[t] = ws;
        }
        __syncthreads();
        #pragma unroll
        for (int kq = 0; kq < 3; ++kq) {
          int c = t + kq * 256;
          int h2 = c >> 6;
          float acc = wself_s[h2] * (float)zh[(size_t)R * DD + c];
          for (int j = 0; j < dg; ++j)
            acc = fmaf(wbuf[j * NH + h2], (float)zh[(size_t)nb_s[j] * DD + c], acc);
          float o = acc / den_s[h2] + bias[c];
          if (do_elu) o = o > 0.f ? o : expm1f(o);
          Oh[(size_t)R * DD + c] = (_Float16)o;
        }
      }
    } else {
      if (blockIdx.x < 192) {
        int g = blockIdx.x / 12, h = blockIdx.x % 12;
        int base = g * 196;
        int w = t >> 6, d = t & 63;
        float er0 = er[(size_t)base * NH + h];
        float lg = -INFINITY;
        if (t < 196) {
          lg = leaky(el[(size_t)(base + t) * NH + h] + er0);
          if (t == 0) lg += LOG2F_;
        }
        float m = lg;
        #pragma unroll
        for (int o = 32; o; o >>= 1) m = fmaxf(m, __shfl_xor(m, o));
        if ((t & 63) == 0) red4[w] = m;
        __syncthreads();
        float mx = fmaxf(fmaxf(red4[0], red4[1]), fmaxf(red4[2], red4[3]));
        float wgt = (t < 196) ? expf(lg - mx) : 0.f;
        if (t < 196) wb[t] = wgt;
        float dn = wgt;
        #pragma unroll
        for (int o = 32; o; o >>= 1) dn += __shfl_xor(dn, o);
        __syncthreads();
        if ((t & 63) == 0) red4[w] = dn;
        __syncthreads();
        float den = red4[0] + red4[1] + red4[2] + red4[3];
        float acc = 0.f;
        int p0 = w * 49;
        #pragma unroll 7
        for (int p = p0; p < p0 + 49; ++p)
          acc = fmaf(wb[p], (float)zh[(size_t)(base + p) * DD + h * DHD + d], acc);
        accP[w][d] = acc;
        __syncthreads();
        if (w == 0) {
          float o = (accP[0][d] + accP[1][d] + accP[2][d] + accP[3][d]) / den + bias[h * DHD + d];
          if (do_elu) o = o > 0.f ? o : expm1f(o);
          int c = h * DHD + d;
          Oh[(size_t)base * DD + c] = (_Float16)o;
          float* root_out = (L == 7) ? out : hroot;
          root_out[(size_t)g * DD + c] = o;
        }
      }
    }
    gridbar(gbar, 2 * L + 1);
  }
}

extern "C" void kernel_launch(void* const* d_in, const int* in_sizes, int n_in,
                              void* d_out, int out_size, void* d_ws, size_t ws_size,
                              hipStream_t stream) {
  const float* l_feat = (const float*)d_in[0];
  const float* r_feat = (const float*)d_in[1];
  const float* W      = (const float*)d_in[2];   // (4, 768, 768)
  const float* a_src  = (const float*)d_in[3];   // (4, 12, 64)
  const float* a_dst  = (const float*)d_in[4];
  const float* b      = (const float*)d_in[5];   // (4, 768)
  float* out = (float*)d_out;

  float* el    = (float*)d_ws;                   // NTOT*NH
  float* er    = el + (size_t)NTOT * NH;         // NTOT*NH
  float* norms = er + (size_t)NTOT * NH;         // NTOT
  float* hroot = norms + NTOT;                   // 16*DD scratch
  unsigned* mask = (unsigned*)(hroot + 16 * DD); // NL*WPR
  int* nbr = (int*)(mask + (size_t)NL * WPR);    // NL*MAXDEG
  int* deg = nbr + (size_t)NL * MAXDEG;          // NL
  _Float16* hhiA = (_Float16*)(deg + NL);        // NTOT*DD halves (ping)
  _Float16* hhiB = hhiA + (size_t)NTOT * DD;     // NTOT*DD halves (pong)
  _Float16* Wthi = hhiB + (size_t)NTOT * DD;     // 4*DD*DD halves
  _Float16* zh   = Wthi + (size_t)4 * DD * DD;   // NTOT*DD halves (fp16 z)
  unsigned* bcnt = (unsigned*)(zh + (size_t)NTOT * DD);  // 1 counter (+pad)
  int2* blist    = (int2*)(bcnt + 2);            // LISTCAP pairs
  unsigned* gbar = (unsigned*)(blist + LISTCAP); // 16 barrier slots

  conv_init<<<NTOT, 192, 0, stream>>>(l_feat, r_feat, hhiA, norms);
  transp_W<<<dim3(24, 24, 4), 256, 0, stream>>>(W, Wthi);
  hipMemsetAsync(bcnt, 0, 4, stream);
  hipMemsetAsync(gbar, 0, 16 * sizeof(unsigned), stream);
  mask_mfma<<<dim3(25, 25), 256, 0, stream>>>(hhiA, norms, mask, bcnt, blist);
  mask_fix<<<32, 256, 0, stream>>>(l_feat, r_feat, norms, bcnt, blist, mask);
  build_csr<<<(NL + 63) / 64, 64, 0, stream>>>(mask, nbr, deg);

  mega<<<GRID_MEGA, 256, 0, stream>>>(hhiA, hhiB, Wthi, a_src, a_dst, b,
                                      zh, el, er, nbr, deg, out, hroot, gbar);
}

// Round 18
// 267.341 us; speedup vs baseline: 13.9332x; 13.9332x over previous
//
#include <hip/hip_runtime.h>
#include <math.h>

// Problem constants
#define NL    1568          // left nodes (B*P)
#define NTOT  3136          // total nodes
#define DD    768           // feature dim
#define NH    12            // heads
#define DHD   64            // head dim
#define WPR   49            // mask words per row (1568/32)
#define MAXDEG 64           // neighbor-list capacity
#define NKSTEP 24           // 768 / 32
#define LISTCAP 16384       // borderline-pair list capacity (~760 expected)
#define LOG2F_ 0.69314718055994530942f

typedef _Float16 h8 __attribute__((ext_vector_type(8)));
typedef float f32x4 __attribute__((ext_vector_type(4)));
#define MFMA16(a, b, c) __builtin_amdgcn_mfma_f32_16x16x32_f16(a, b, c, 0, 0, 0)

__device__ __forceinline__ float leaky(float x) { return x > 0.f ? x : 0.2f * x; }

__device__ __forceinline__ void gld16(const _Float16* g, _Float16* l) {
  __builtin_amdgcn_global_load_lds(
      (const __attribute__((address_space(1))) void*)g,
      (__attribute__((address_space(3))) void*)l, 16, 0, 0);
}

// ---------------------------------------------------------------- fused setup: conv rows (blocks 0..3135) + W transpose (3136..5439)
__global__ __launch_bounds__(256) void setup_fused(const float* __restrict__ lf, const float* __restrict__ rf,
                                                   const float* __restrict__ W,
                                                   _Float16* __restrict__ hi, float* __restrict__ norms,
                                                   _Float16* __restrict__ Wthi) {
  int t = threadIdx.x;
  if (blockIdx.x < NTOT) {
    // ---- conv_init: one row per block, 192 active threads (row = 192 float4)
    int n = blockIdx.x;
    __shared__ float red[3];
    float s = 0.f;
    if (t < 192) {
      const float* src = (n < NL) ? lf + (size_t)n * DD : rf + (size_t)(n - NL) * DD;
      float4 v = reinterpret_cast<const float4*>(src)[t];
      typedef _Float16 h4v __attribute__((ext_vector_type(4)));
      h4v hv = {(_Float16)v.x, (_Float16)v.y, (_Float16)v.z, (_Float16)v.w};
      reinterpret_cast<h4v*>(hi)[(size_t)n * (DD / 4) + t] = hv;
      s = v.x * v.x + v.y * v.y + v.z * v.z + v.w * v.w;
    }
    #pragma unroll
    for (int o = 32; o; o >>= 1) s += __shfl_xor(s, o);
    if (t < 192 && (t & 63) == 0) red[t >> 6] = s;
    __syncthreads();
    if (t == 0) norms[n] = sqrtf(red[0] + red[1] + red[2]);
  } else {
    // ---- transp_W: W[i][k][n] -> Wt[i][n][k] fp16
    int bid = blockIdx.x - NTOT;
    int i = bid / 576;                 // 24*24 = 576 tiles per layer
    int rem = bid - i * 576;
    int ktile = rem / 24, ntile = rem % 24;
    __shared__ float tile[32][33];
    int kt = ktile * 32, nt = ntile * 32;
    int tx = t & 31, ty = t >> 5;
    const float* Wp = W + ((size_t)i * DD + kt) * DD + nt;
    #pragma unroll
    for (int p = 0; p < 4; ++p) tile[ty + p * 8][tx] = Wp[(size_t)(ty + p * 8) * DD + tx];
    __syncthreads();
    _Float16* oh = Wthi + ((size_t)i * DD + nt) * DD + kt;
    #pragma unroll
    for (int p = 0; p < 4; ++p) {
      int nn = ty + p * 8;
      oh[(size_t)nn * DD + tx] = (_Float16)tile[tx][nn];
    }
  }
}

// ---------------------------------------------------------------- LDS-staged MFMA GEMM (pure fp16, BK=32) + fused epilogue
// R9-proven structure. grid 588 (XCD-swizzled). 256 thr = 4 waves x 16 rows. fp16 z out.
__global__ __launch_bounds__(256) void gemm_mfma(const _Float16* __restrict__ Ahi,
                                                 const _Float16* __restrict__ Bhi,
                                                 const float* __restrict__ a_s, const float* __restrict__ a_d,
                                                 const float* __restrict__ bias,
                                                 _Float16* __restrict__ zh,
                                                 float* __restrict__ el, float* __restrict__ er,
                                                 _Float16* __restrict__ ohhi,
                                                 int do_elu, int mode) {
  __shared__ _Float16 sm[2][2][2048];   // [buf][Ahi,Bhi][64*32]
  int t = threadIdx.x;
  // bijective XCD swizzle: 588 = 4*74 + 4*73
  int xcd = blockIdx.x & 7, pos = blockIdx.x >> 3;
  int orig = (xcd < 4 ? xcd * 74 : 296 + (xcd - 4) * 73) + pos;
  int bx = orig / 12, by = orig % 12;
  int m0 = bx * 64, n0 = by * 64;

  int rl = t >> 2;
  int kq_src = (t & 3) ^ ((t >> 3) & 3);
  size_t aoff = (size_t)(m0 + rl) * DD + kq_src * 8;
  size_t boff = (size_t)(n0 + rl) * DD + kq_src * 8;
  const _Float16* pAhi = Ahi + aoff;
  const _Float16* pBhi = Bhi + boff;
  int ch = (t >> 6) * 512;             // wave-uniform LDS chunk (halves)

  int ln = t & 63, wv = t >> 6;
  int fr = ln & 15, kg = ln >> 4;
  int kq8 = (kg ^ ((fr >> 1) & 3)) * 8;  // swizzled fragment k-offset (halves)
  int aRead = (wv * 16 + fr) * 32 + kq8;

  f32x4 zero = {0.f, 0.f, 0.f, 0.f};
  f32x4 acc[4];
  #pragma unroll
  for (int cg = 0; cg < 4; ++cg) acc[cg] = zero;

  gld16(pAhi, &sm[0][0][ch]);
  gld16(pBhi, &sm[0][1][ch]);
  __syncthreads();

  for (int step = 0; step < NKSTEP; ++step) {
    int buf = step & 1;
    if (step < NKSTEP - 1) {
      int kb = (step + 1) * 32;
      gld16(pAhi + kb, &sm[buf ^ 1][0][ch]);
      gld16(pBhi + kb, &sm[buf ^ 1][1][ch]);
    }
    h8 ah = *reinterpret_cast<const h8*>(&sm[buf][0][aRead]);
    #pragma unroll
    for (int cg = 0; cg < 4; ++cg) {
      int bRead = (cg * 16 + fr) * 32 + kq8;
      h8 bh = *reinterpret_cast<const h8*>(&sm[buf][1][bRead]);
      acc[cg] = MFMA16(ah, bh, acc[cg]);
    }
    __syncthreads();
  }

  int head = by;
  int orow = m0 + wv * 16 + kg * 4;
  // z (fp16) + fused h-plane write
  #pragma unroll
  for (int i = 0; i < 4; ++i) {
    int r = orow + i;
    bool wh = (mode == 0) ? (r < NL) : (r % 196 != 0);
    #pragma unroll
    for (int cg = 0; cg < 4; ++cg) {
      int c = n0 + cg * 16 + fr;
      float z = acc[cg][i];
      zh[(size_t)r * DD + c] = (_Float16)z;
      if (wh) {
        float o = z + bias[c];
        if (do_elu) o = o > 0.f ? o : expm1f(o);
        ohhi[(size_t)r * DD + c] = (_Float16)o;
      }
    }
  }
  // fused el/er (this block owns head == by)
  float asv[4], adv[4];
  #pragma unroll
  for (int cg = 0; cg < 4; ++cg) {
    asv[cg] = a_s[head * DHD + cg * 16 + fr];
    adv[cg] = a_d[head * DHD + cg * 16 + fr];
  }
  #pragma unroll
  for (int i = 0; i < 4; ++i) {
    float s1 = 0.f, s2 = 0.f;
    #pragma unroll
    for (int cg = 0; cg < 4; ++cg) {
      s1 = fmaf(acc[cg][i], asv[cg], s1);
      s2 = fmaf(acc[cg][i], adv[cg], s2);
    }
    #pragma unroll
    for (int o = 1; o < 16; o <<= 1) {
      s1 += __shfl_xor(s1, o);
      s2 += __shfl_xor(s2, o);
    }
    if (fr == 0) {
      el[(size_t)(orow + i) * NH + head] = s1;
      er[(size_t)(orow + i) * NH + head] = s2;
    }
  }
}

// ---------------------------------------------------------------- mask via hi-only MFMA; borderline pairs -> list
// dot error sigma ~1e-2; band +-0.5 = 50 sigma. Non-borderline bits exact; borderline fixed by mask_fix.
__global__ __launch_bounds__(256) void mask_mfma(const _Float16* __restrict__ Hhi,
                                                 const float* __restrict__ norms, unsigned* __restrict__ mask,
                                                 unsigned* __restrict__ bcnt, int2* __restrict__ blist) {
  __shared__ _Float16 sm[2][2][2048];
  __shared__ unsigned mw[64][2];
  int t = threadIdx.x;
  int r0 = blockIdx.x * 64, l0 = blockIdx.y * 64;

  int rl = t >> 2;
  int kq_src = (t & 3) ^ ((t >> 3) & 3);
  int ra = r0 + rl; if (ra >= NL) ra = NL - 1;
  int la = l0 + rl; if (la >= NL) la = NL - 1;
  const _Float16* pA = Hhi + (size_t)(NL + ra) * DD + kq_src * 8;
  const _Float16* pB = Hhi + (size_t)la * DD + kq_src * 8;
  int ch = (t >> 6) * 512;

  int ln = t & 63, wv = t >> 6;
  int fr = ln & 15, kg = ln >> 4;
  int kq8 = (kg ^ ((fr >> 1) & 3)) * 8;
  int aRead = (wv * 16 + fr) * 32 + kq8;

  f32x4 zero = {0.f, 0.f, 0.f, 0.f};
  f32x4 acc[4];
  #pragma unroll
  for (int cg = 0; cg < 4; ++cg) acc[cg] = zero;
  if (t < 128) mw[t >> 1][t & 1] = 0u;

  gld16(pA, &sm[0][0][ch]);
  gld16(pB, &sm[0][1][ch]);
  __syncthreads();

  for (int step = 0; step < NKSTEP; ++step) {
    int buf = step & 1;
    if (step < NKSTEP - 1) {
      int kb = (step + 1) * 32;
      gld16(pA + kb, &sm[buf ^ 1][0][ch]);
      gld16(pB + kb, &sm[buf ^ 1][1][ch]);
    }
    h8 ah = *reinterpret_cast<const h8*>(&sm[buf][0][aRead]);
    #pragma unroll
    for (int cg = 0; cg < 4; ++cg) {
      int bRead = (cg * 16 + fr) * 32 + kq8;
      h8 bh = *reinterpret_cast<const h8*>(&sm[buf][1][bRead]);
      acc[cg] = MFMA16(ah, bh, acc[cg]);
    }
    __syncthreads();
  }

  int rloc = wv * 16 + kg * 4;
  float nrv[4];
  #pragma unroll
  for (int i = 0; i < 4; ++i) {
    int r = r0 + rloc + i;
    nrv[i] = norms[NL + (r < NL ? r : NL - 1)];
  }
  #pragma unroll
  for (int cg = 0; cg < 4; ++cg) {
    int lloc = cg * 16 + fr;
    int l = l0 + lloc;
    float nlv = norms[l < NL ? l : NL - 1];
    #pragma unroll
    for (int i = 0; i < 4; ++i) {
      int r = r0 + rloc + i;
      if (r >= NL || l >= NL) continue;
      float thr = 0.1f * nrv[i] * nlv;
      float dot = acc[cg][i];
      if (fabsf(dot - thr) <= 0.5f) {
        unsigned pos = atomicAdd(bcnt, 1u);
        if (pos < LISTCAP) blist[pos] = make_int2(r, l);
      }
      if (dot > thr) atomicOr(&mw[rloc + i][lloc >> 5], 1u << (lloc & 31));
    }
  }
  __syncthreads();
  if (t < 128) {
    int rr = t >> 1, w = t & 1;
    int rg = r0 + rr, wg = blockIdx.y * 2 + w;
    if (rg < NL && wg < WPR) mask[(size_t)rg * WPR + wg] = mw[rr][w];
  }
}

// ---------------------------------------------------------------- exact fp32 recheck of borderline pairs (wave/pair)
__global__ __launch_bounds__(256) void mask_fix(const float* __restrict__ lf, const float* __restrict__ rf,
                                                const float* __restrict__ norms,
                                                const unsigned* __restrict__ bcnt, const int2* __restrict__ blist,
                                                unsigned* __restrict__ mask) {
  unsigned cnt = *bcnt;
  if (cnt > LISTCAP) cnt = LISTCAP;
  int lane = threadIdx.x & 63;
  unsigned wid = blockIdx.x * 4 + (threadIdx.x >> 6);
  for (unsigned idx = wid; idx < cnt; idx += gridDim.x * 4) {
    int2 pr = blist[idx];
    int r = pr.x, l = pr.y;
    const float4* rp = reinterpret_cast<const float4*>(rf + (size_t)r * DD);
    const float4* lp = reinterpret_cast<const float4*>(lf + (size_t)l * DD);
    float s = 0.f;
    #pragma unroll
    for (int k = 0; k < 3; ++k) {
      float4 a = rp[lane + k * 64], b = lp[lane + k * 64];
      s = fmaf(a.x, b.x, s); s = fmaf(a.y, b.y, s);
      s = fmaf(a.z, b.z, s); s = fmaf(a.w, b.w, s);
    }
    #pragma unroll
    for (int o = 32; o; o >>= 1) s += __shfl_xor(s, o);
    if (lane == 0) {
      float thr = 0.1f * norms[NL + r] * norms[l];
      unsigned* wp = &mask[(size_t)r * WPR + (l >> 5)];
      unsigned bit = 1u << (l & 31);
      if (s > thr) atomicOr(wp, bit);
      else atomicAnd(wp, ~bit);
    }
  }
}

// ---------------------------------------------------------------- build neighbor lists from bitmask (once)
__global__ __launch_bounds__(64) void build_csr(const unsigned* __restrict__ mask,
                                                int* __restrict__ nbr, int* __restrict__ deg) {
  int r = blockIdx.x * 64 + threadIdx.x;
  if (r >= NL) return;
  const unsigned* mr = mask + (size_t)r * WPR;
  int* out = nbr + (size_t)r * MAXDEG;
  int cnt = 0;
  #pragma unroll 7
  for (int w = 0; w < WPR; ++w) {
    unsigned m = mr[w];
    while (m) {
      int bpos = __ffs(m) - 1;
      m &= m - 1;
      if (cnt < MAXDEG) out[cnt] = w * 32 + bpos;
      ++cnt;
    }
  }
  deg[r] = cnt < MAXDEG ? cnt : MAXDEG;
}

// ---------------------------------------------------------------- fused sparse bipartite attention (z in fp16)
__global__ __launch_bounds__(768) void bip_fused(const _Float16* __restrict__ zh, const float* __restrict__ el,
                                                 const float* __restrict__ er, const int* __restrict__ nbr,
                                                 const int* __restrict__ deg, const float* __restrict__ bias,
                                                 _Float16* __restrict__ ohhi,
                                                 int do_elu) {
  int r = blockIdx.x;
  int R = NL + r;
  int t = threadIdx.x;
  int dg = deg[r];
  __shared__ int nb_s[MAXDEG];
  __shared__ float wbuf[MAXDEG * NH];
  __shared__ float den_s[NH], wself_s[NH];
  if (t < dg) nb_s[t] = nbr[(size_t)r * MAXDEG + t];
  __syncthreads();
  if (t < dg * NH) {
    int j = t / NH, h2 = t - j * NH;
    wbuf[t] = el[(size_t)nb_s[j] * NH + h2];
  }
  __syncthreads();
  if (t < NH) {
    float er_r = er[(size_t)R * NH + t];
    float s = leaky(el[(size_t)R * NH + t] + er_r);
    float mx = s;
    for (int j = 0; j < dg; ++j) mx = fmaxf(mx, leaky(wbuf[j * NH + t] + er_r));
    float den = 0.f;
    for (int j = 0; j < dg; ++j) {
      float w = expf(leaky(wbuf[j * NH + t] + er_r) - mx);
      wbuf[j * NH + t] = w;
      den += w;
    }
    float ws = expf(s - mx);
    den_s[t] = den + ws;
    wself_s[t] = ws;
  }
  __syncthreads();
  int h2 = t >> 6;
  float acc = wself_s[h2] * (float)zh[(size_t)R * DD + t];
  for (int j = 0; j < dg; ++j)
    acc = fmaf(wbuf[j * NH + h2], (float)zh[(size_t)nb_s[j] * DD + t], acc);
  float o = acc / den_s[h2] + bias[t];
  if (do_elu) o = o > 0.f ? o : expm1f(o);
  ohhi[(size_t)R * DD + t] = (_Float16)o;
}

// ---------------------------------------------------------------- pool attention, (group, head) per block, 4 waves
__global__ __launch_bounds__(256) void pool_attn2(const _Float16* __restrict__ zh, const float* __restrict__ el,
                                                  const float* __restrict__ er, const float* __restrict__ bias,
                                                  _Float16* __restrict__ ohhi,
                                                  float* __restrict__ root_out, int do_elu) {
  int g = blockIdx.x, h = blockIdx.y;
  int base = g * 196;
  int t = threadIdx.x;
  int w = t >> 6, d = t & 63;
  __shared__ float wb[196];
  __shared__ float red[4];
  __shared__ float accP[4][64];
  float er0 = er[(size_t)base * NH + h];
  float lg = -INFINITY;
  if (t < 196) {
    lg = leaky(el[(size_t)(base + t) * NH + h] + er0);
    if (t == 0) lg += LOG2F_;
  }
  float m = lg;
  #pragma unroll
  for (int o = 32; o; o >>= 1) m = fmaxf(m, __shfl_xor(m, o));
  if ((t & 63) == 0) red[w] = m;
  __syncthreads();
  float mx = fmaxf(fmaxf(red[0], red[1]), fmaxf(red[2], red[3]));
  float wgt = (t < 196) ? expf(lg - mx) : 0.f;
  if (t < 196) wb[t] = wgt;
  float dn = wgt;
  #pragma unroll
  for (int o = 32; o; o >>= 1) dn += __shfl_xor(dn, o);
  __syncthreads();
  if ((t & 63) == 0) red[w] = dn;
  __syncthreads();
  float den = red[0] + red[1] + red[2] + red[3];
  float acc = 0.f;
  int p0 = w * 49;
  #pragma unroll 7
  for (int p = p0; p < p0 + 49; ++p)
    acc = fmaf(wb[p], (float)zh[(size_t)(base + p) * DD + h * DHD + d], acc);
  accP[w][d] = acc;
  __syncthreads();
  if (w == 0) {
    float o = (accP[0][d] + accP[1][d] + accP[2][d] + accP[3][d]) / den + bias[h * DHD + d];
    if (do_elu) o = o > 0.f ? o : expm1f(o);
    int c = h * DHD + d;
    ohhi[(size_t)base * DD + c] = (_Float16)o;
    root_out[(size_t)g * DD + c] = o;
  }
}

extern "C" void kernel_launch(void* const* d_in, const int* in_sizes, int n_in,
                              void* d_out, int out_size, void* d_ws, size_t ws_size,
                              hipStream_t stream) {
  const float* l_feat = (const float*)d_in[0];
  const float* r_feat = (const float*)d_in[1];
  const float* W      = (const float*)d_in[2];   // (4, 768, 768)
  const float* a_src  = (const float*)d_in[3];   // (4, 12, 64)
  const float* a_dst  = (const float*)d_in[4];
  const float* b      = (const float*)d_in[5];   // (4, 768)
  float* out = (float*)d_out;

  float* el    = (float*)d_ws;                   // NTOT*NH
  float* er    = el + (size_t)NTOT * NH;         // NTOT*NH
  float* norms = er + (size_t)NTOT * NH;         // NTOT
  float* hroot = norms + NTOT;                   // 16*DD scratch
  unsigned* mask = (unsigned*)(hroot + 16 * DD); // NL*WPR
  int* nbr = (int*)(mask + (size_t)NL * WPR);    // NL*MAXDEG
  int* deg = nbr + (size_t)NL * MAXDEG;          // NL
  _Float16* hhiA = (_Float16*)(deg + NL);        // NTOT*DD halves (ping)
  _Float16* hhiB = hhiA + (size_t)NTOT * DD;     // NTOT*DD halves (pong)
  _Float16* Wthi = hhiB + (size_t)NTOT * DD;     // 4*DD*DD halves
  _Float16* zh   = Wthi + (size_t)4 * DD * DD;   // NTOT*DD halves (fp16 z)
  unsigned* bcnt = (unsigned*)(zh + (size_t)NTOT * DD);  // 1 counter (+pad)
  int2* blist    = (int2*)(bcnt + 2);            // LISTCAP pairs

  _Float16* hhi[2] = {hhiA, hhiB};

  hipMemsetAsync(bcnt, 0, 4, stream);
  setup_fused<<<NTOT + 2304, 256, 0, stream>>>(l_feat, r_feat, W, hhiA, norms, Wthi);
  mask_mfma<<<dim3(25, 25), 256, 0, stream>>>(hhiA, norms, mask, bcnt, blist);
  mask_fix<<<32, 256, 0, stream>>>(l_feat, r_feat, norms, bcnt, blist, mask);
  build_csr<<<(NL + 63) / 64, 64, 0, stream>>>(mask, nbr, deg);

  // ---- 4 bipartite layers (ping-pong h planes: layer L reads L&1, writes (L+1)&1)
  for (int i = 0; i < 4; ++i) {
    const float* bi = b + (size_t)i * DD;
    int do_elu = (i < 3) ? 1 : 0;
    int ib = i & 1, ob = (i + 1) & 1;
    gemm_mfma<<<588, 256, 0, stream>>>(hhi[ib],
        Wthi + (size_t)i * DD * DD,
        a_src + (size_t)i * NH * DHD, a_dst + (size_t)i * NH * DHD,
        bi, zh, el, er, hhi[ob], do_elu, 0);
    bip_fused<<<NL, 768, 0, stream>>>(zh, el, er, nbr, deg, bi, hhi[ob], do_elu);
  }

  // ---- 4 pool layers
  for (int i = 0; i < 4; ++i) {
    const float* bi = b + (size_t)i * DD;
    int do_elu = (i < 3) ? 1 : 0;
    int L = 4 + i;
    int ib = L & 1, ob = (L + 1) & 1;
    gemm_mfma<<<588, 256, 0, stream>>>(hhi[ib],
        Wthi + (size_t)i * DD * DD,
        a_src + (size_t)i * NH * DHD, a_dst + (size_t)i * NH * DHD,
        bi, zh, el, er, hhi[ob], do_elu, 1);
    pool_attn2<<<dim3(16, NH), 256, 0, stream>>>(zh, el, er, bi, hhi[ob],
        (i == 3) ? out : hroot, do_elu);
  }
}